// Round 11
// baseline (174.475 us; speedup 1.0000x reference)
//
#include <hip/hip_runtime.h>

// Problem constants (fixed by the reference):
//   expert_outputs: [E=8, C=8192, D=1024] f32
//   weights:        [E, C] f32
//   token_indices:  [E, C] int32 (harness converts integer inputs to int32)
//   out:            [B=8, S=4096, D=1024] f32  (flat: 32768 x 1024)
#define E_EXP 8
#define C_CAP 8192
#define D_DIM 1024
#define N_ROWS (E_EXP * C_CAP)        // 65536  (row ids fit in ushort)
#define N_TOK  (8 * 4096)             // 32768
#define SLOTS_K 16                    // slots/token (Poisson(2): P(>16) ~ 1e-12)
#define NBLK 1024                     // 4 blocks/CU x 256 CU -> co-resident
#define ROWS_PER_BLK (N_ROWS / NBLK)  // 64 (one wave's worth of build work)
#define TOK_PER_BLK (N_TOK / NBLK)    // 32
#define TOK_PER_WAVE (TOK_PER_BLK / 4) // 8

typedef float f32x4 __attribute__((ext_vector_type(4)));

// Cached loads for expert rows: input is ~50% L3-resident across replays
// (round-8 A/B: cached vs NT loads = -14 us; round-9 FETCH 135 MB vs 262 MB).
__device__ __forceinline__ f32x4 ld4(const float* p) {
    return *reinterpret_cast<const f32x4*>(p);
}

// Gather N rows into 4 chunk-accumulators. All 4*N row loads independent.
template<int N>
__device__ __forceinline__ void gather_rows(const float* __restrict__ eo,
                                            const float* __restrict__ w,
                                            const unsigned short* __restrict__ id,
                                            int lane, f32x4 acc[4])
{
    int row[N];
    #pragma unroll
    for (int r = 0; r < N; ++r) row[r] = id[r];
    float wt[N];
    #pragma unroll
    for (int r = 0; r < N; ++r) wt[r] = w[row[r]];
    f32x4 v[N][4];
    #pragma unroll
    for (int r = 0; r < N; ++r) {
        const float* base = eo + (size_t)row[r] * D_DIM + lane * 4;
        #pragma unroll
        for (int c = 0; c < 4; ++c)
            v[r][c] = ld4(base + c * 256);            // 4 indep 1KB-wide loads
    }
    #pragma unroll
    for (int r = 0; r < N; ++r) {
        #pragma unroll
        for (int c = 0; c < 4; ++c) acc[c] += wt[r] * v[r][c];
    }
}

// ONE kernel: build inverse index -> grid barrier -> gather.
// Round-9 lesson: the barrier itself was fine (correct results); the 2x
// regression was ACQUIRE-polling every ~128 cycles = continuous XCD-L2
// invalidates. Fix: poll every s_sleep(64) ~ 4096 cycles (~1.7 us), so
// aggregate invalidate rate is negligible. Build spread over all blocks
// (64 rows each) to minimize barrier arrival skew.
__global__ __launch_bounds__(256, 4) void combine_fused(
    const float* __restrict__ expert_outputs,
    const float* __restrict__ weights,
    const int* __restrict__ token_indices,
    int* __restrict__ count,            // [N_TOK] in d_ws, pre-zeroed
    unsigned short* __restrict__ slots, // [N_TOK * SLOTS_K] in d_ws
    int* __restrict__ bar,              // [1] in d_ws, pre-zeroed
    float* __restrict__ out)
{
    // ---- Phase 1: build inverse index (64 rows per block) ----
    if (threadIdx.x < ROWS_PER_BLK) {
        const int row = blockIdx.x * ROWS_PER_BLK + threadIdx.x;
        const int tok = token_indices[row];
        const int slot = atomicAdd(&count[tok], 1);   // device-scope default
        if (slot < SLOTS_K)
            slots[(size_t)tok * SLOTS_K + slot] = (unsigned short)row;
        // Tokens exceeding SLOTS_K rows take the exact rescan path below.
    }

    // ---- Grid barrier: release-add, then SLOW acquire-poll ----
    __syncthreads();
    if (threadIdx.x == 0) {
        __hip_atomic_fetch_add(bar, 1, __ATOMIC_RELEASE,
                               __HIP_MEMORY_SCOPE_AGENT);
        while (__hip_atomic_load(bar, __ATOMIC_ACQUIRE,
                                 __HIP_MEMORY_SCOPE_AGENT) < NBLK)
            __builtin_amdgcn_s_sleep(64);   // ~4096 cyc between polls
    }
    __syncthreads();

    // ---- Phase 2: gather, one wave per token, 8 tokens per wave ----
    const int wv   = threadIdx.x >> 6;                // 0..3
    const int lane = threadIdx.x & 63;
    const int tokBase = blockIdx.x * TOK_PER_BLK + wv * TOK_PER_WAVE;

    for (int j = 0; j < TOK_PER_WAVE; ++j) {
        const int tok = tokBase + j;
        const int n = count[tok];
        const unsigned short* sl = slots + (size_t)tok * SLOTS_K;

        f32x4 acc[4];
        #pragma unroll
        for (int c = 0; c < 4; ++c) acc[c] = (f32x4)(0.f);

        if (__builtin_expect(n <= SLOTS_K, 1)) {
            switch (n) {
            case 0: break;
            case 1: gather_rows<1>(expert_outputs, weights, sl, lane, acc); break;
            case 2: gather_rows<2>(expert_outputs, weights, sl, lane, acc); break;
            case 3: gather_rows<3>(expert_outputs, weights, sl, lane, acc); break;
            default: {
                int r = 0;
                for (; r + 2 <= n; r += 2)
                    gather_rows<2>(expert_outputs, weights, sl + r, lane, acc);
                if (r < n)
                    gather_rows<1>(expert_outputs, weights, sl + r, lane, acc);
            } }
        } else {
            // Exact rare path (n > SLOTS_K: ~impossible for this input).
            for (int row = 0; row < N_ROWS; ++row) {
                if (token_indices[row] == tok) {
                    const float w = weights[row];
                    const float* base =
                        expert_outputs + (size_t)row * D_DIM + lane * 4;
                    #pragma unroll
                    for (int c = 0; c < 4; ++c) acc[c] += w * ld4(base + c * 256);
                }
            }
        }

        // NT store: output is write-once; don't evict the reused input.
        // Zero tokens included -> output fully initialized, poison-safe.
        float* ob = out + (size_t)tok * D_DIM + lane * 4;
        #pragma unroll
        for (int c = 0; c < 4; ++c)
            __builtin_nontemporal_store(acc[c],
                reinterpret_cast<f32x4*>(ob + c * 256));
    }
}

extern "C" void kernel_launch(void* const* d_in, const int* in_sizes, int n_in,
                              void* d_out, int out_size, void* d_ws, size_t ws_size,
                              hipStream_t stream) {
    const float* expert_outputs = (const float*)d_in[0];
    const float* weights        = (const float*)d_in[1];
    const int*   token_indices  = (const int*)d_in[2];
    float* out = (float*)d_out;

    // Workspace layout:
    //   count : N_TOK int            (128 KB)
    //   bar   : 1 int                (grid-barrier counter)
    //   slots : N_TOK*SLOTS_K ushort (1 MB)
    int* count = (int*)d_ws;
    int* bar   = count + N_TOK;
    unsigned short* slots = (unsigned short*)(bar + 1);

    // Zero counters + barrier every call (deterministic across replays).
    hipMemsetAsync(count, 0, (size_t)(N_TOK + 1) * sizeof(int), stream);

    combine_fused<<<NBLK, 256, 0, stream>>>(
        expert_outputs, weights, token_indices, count, slots, bar, out);
}

// Round 12
// 74.275 us; speedup vs baseline: 2.3491x; 2.3491x over previous
//
#include <hip/hip_runtime.h>

// Problem constants (fixed by the reference):
//   expert_outputs: [E=8, C=8192, D=1024] f32
//   weights:        [E, C] f32
//   token_indices:  [E, C] int32 (harness converts integer inputs to int32)
//   out:            [B=8, S=4096, D=1024] f32  (flat: 32768 x 1024)
#define E_EXP 8
#define C_CAP 8192
#define D_DIM 1024
#define N_ROWS (E_EXP * C_CAP)        // 65536  (row ids fit in ushort)
#define N_TOK  (8 * 4096)             // 32768
#define SLOTS_K 16                    // slots/token (Poisson(2): P(>16) ~ 1e-12)
#define WV_TOK 4                      // tokens per wave (software-pipelined)
#define GATHER_BLOCKS (N_TOK / (4 * WV_TOK))  // 2048

typedef float f32x4 __attribute__((ext_vector_type(4)));

// Cached loads for expert rows: the 256 MB input is ~50% L3-resident across
// graph replays (round-9 counters: FETCH 135 MB vs 262 MB logical reads;
// round-8 A/B: cached vs NT loads = -14 us).
__device__ __forceinline__ f32x4 ld4(const float* p) {
    return *reinterpret_cast<const f32x4*>(p);
}

// ---------------- Pass 1: build inverse index (token -> row list) ----------
__global__ __launch_bounds__(256) void combine_build(
    const int* __restrict__ token_indices,
    int* __restrict__ count,            // [N_TOK], pre-zeroed
    unsigned short* __restrict__ slots) // [N_TOK * SLOTS_K]
{
    const int row = blockIdx.x * 256 + threadIdx.x;   // 0 .. N_ROWS-1
    const int tok = token_indices[row];
    const int slot = atomicAdd(&count[tok], 1);
    if (slot < SLOTS_K) {
        slots[(size_t)tok * SLOTS_K + slot] = (unsigned short)row;
    }
    // Tokens exceeding SLOTS_K rows take the exact rescan path in gather.
}

// Pick dword w of the 8 slot-id dwords held in two uint4 registers. All call
// sites have compile-time w (full unroll) -> folds to a plain register read.
__device__ __forceinline__ unsigned pickw(const uint4& a, const uint4& b, int w) {
    unsigned r = a.x;
    r = (w == 1) ? a.y : r; r = (w == 2) ? a.z : r; r = (w == 3) ? a.w : r;
    r = (w == 4) ? b.x : r; r = (w == 5) ? b.y : r; r = (w == 6) ? b.z : r;
    r = (w == 7) ? b.w : r;
    return r;
}
__device__ __forceinline__ int sid(const uint4& a, const uint4& b, int r) {
    const unsigned word = pickw(a, b, r >> 1);
    return (r & 1) ? (int)(word >> 16) : (int)(word & 0xFFFFu);
}

// Gather N (<=2) rows; slot ids extracted from registers at constant base+r.
// All 4*N row loads independent and issued back-to-back.
template<int N>
__device__ __forceinline__ void gather_rows(const float* __restrict__ eo,
                                            const float* __restrict__ wts,
                                            const uint4& sa, const uint4& sb,
                                            int base, int lane, f32x4 acc[4])
{
    int row[N];
    #pragma unroll
    for (int r = 0; r < N; ++r) row[r] = sid(sa, sb, base + r);
    float wt[N];
    #pragma unroll
    for (int r = 0; r < N; ++r) wt[r] = wts[row[r]];
    f32x4 v[N][4];
    #pragma unroll
    for (int r = 0; r < N; ++r) {
        const float* bp = eo + (size_t)row[r] * D_DIM + lane * 4;
        #pragma unroll
        for (int c = 0; c < 4; ++c) v[r][c] = ld4(bp + c * 256);
    }
    #pragma unroll
    for (int r = 0; r < N; ++r) {
        #pragma unroll
        for (int c = 0; c < 4; ++c) acc[c] += wt[r] * v[r][c];
    }
}

// Process exactly NN rows in chunks of 2 — every slot extraction uses a
// compile-time index, so ids never leave registers (no scratch, rule #20).
template<int NN>
__device__ __forceinline__ void gather_n(const float* __restrict__ eo,
                                         const float* __restrict__ wts,
                                         const uint4& sa, const uint4& sb,
                                         int lane, f32x4 acc[4])
{
    #pragma unroll
    for (int r = 0; r + 2 <= NN; r += 2)
        gather_rows<2>(eo, wts, sa, sb, r, lane, acc);
    if constexpr (NN & 1)
        gather_rows<1>(eo, wts, sa, sb, NN - 1, lane, acc);
}

// ---------------- Pass 2: one wave per 4 tokens, metadata pipelined --------
__global__ __launch_bounds__(256) void combine_gather(
    const float* __restrict__ expert_outputs,
    const float* __restrict__ weights,
    const int* __restrict__ token_indices,
    const int* __restrict__ count,
    const unsigned short* __restrict__ slots,
    float* __restrict__ out)
{
    const int wv   = threadIdx.x >> 6;                // 0..3
    const int lane = threadIdx.x & 63;
    int tok = blockIdx.x * (4 * WV_TOK) + wv * WV_TOK;

    // slots is 32B-aligned (offset 128 KB into d_ws); 2 uint4 per token.
    const uint4* sp = reinterpret_cast<const uint4*>(slots);

    uint4 sa = sp[2 * tok], sb = sp[2 * tok + 1];
    int ncur = count[tok];

    #pragma unroll
    for (int j = 0; j < WV_TOK; ++j) {
        // Prefetch next token's metadata (compile-time guard; loads issue
        // before the current token's row loads and complete under them).
        uint4 na = {0, 0, 0, 0}, nb = {0, 0, 0, 0};
        int nn = 0;
        if (j < WV_TOK - 1) {
            na = sp[2 * (tok + 1)];
            nb = sp[2 * (tok + 1) + 1];
            nn = count[tok + 1];
        }

        f32x4 acc[4];
        #pragma unroll
        for (int c = 0; c < 4; ++c) acc[c] = (f32x4)(0.f);

        if (__builtin_expect(ncur <= SLOTS_K, 1)) {
            switch (ncur) {
            case 0: break;
            case 1:  gather_n<1>(expert_outputs, weights, sa, sb, lane, acc); break;
            case 2:  gather_n<2>(expert_outputs, weights, sa, sb, lane, acc); break;
            case 3:  gather_n<3>(expert_outputs, weights, sa, sb, lane, acc); break;
            case 4:  gather_n<4>(expert_outputs, weights, sa, sb, lane, acc); break;
            case 5:  gather_n<5>(expert_outputs, weights, sa, sb, lane, acc); break;
            case 6:  gather_n<6>(expert_outputs, weights, sa, sb, lane, acc); break;
            case 7:  gather_n<7>(expert_outputs, weights, sa, sb, lane, acc); break;
            case 8:  gather_n<8>(expert_outputs, weights, sa, sb, lane, acc); break;
            case 9:  gather_n<9>(expert_outputs, weights, sa, sb, lane, acc); break;
            case 10: gather_n<10>(expert_outputs, weights, sa, sb, lane, acc); break;
            case 11: gather_n<11>(expert_outputs, weights, sa, sb, lane, acc); break;
            case 12: gather_n<12>(expert_outputs, weights, sa, sb, lane, acc); break;
            case 13: gather_n<13>(expert_outputs, weights, sa, sb, lane, acc); break;
            case 14: gather_n<14>(expert_outputs, weights, sa, sb, lane, acc); break;
            case 15: gather_n<15>(expert_outputs, weights, sa, sb, lane, acc); break;
            default: gather_n<16>(expert_outputs, weights, sa, sb, lane, acc); break;
            }
        } else {
            // Exact rare path (ncur > SLOTS_K: ~impossible, P ~ 1e-12/token).
            for (int row = 0; row < N_ROWS; ++row) {
                if (token_indices[row] == tok) {
                    const float w = weights[row];
                    const float* bp =
                        expert_outputs + (size_t)row * D_DIM + lane * 4;
                    #pragma unroll
                    for (int c = 0; c < 4; ++c) acc[c] += w * ld4(bp + c * 256);
                }
            }
        }

        // NT store: output is write-once; don't evict the reused input.
        // Zero tokens included -> output fully initialized, poison-safe.
        float* ob = out + (size_t)tok * D_DIM + lane * 4;
        #pragma unroll
        for (int c = 0; c < 4; ++c)
            __builtin_nontemporal_store(acc[c],
                reinterpret_cast<f32x4*>(ob + c * 256));

        sa = na; sb = nb; ncur = nn; ++tok;
    }
}

extern "C" void kernel_launch(void* const* d_in, const int* in_sizes, int n_in,
                              void* d_out, int out_size, void* d_ws, size_t ws_size,
                              hipStream_t stream) {
    const float* expert_outputs = (const float*)d_in[0];
    const float* weights        = (const float*)d_in[1];
    const int*   token_indices  = (const int*)d_in[2];
    float* out = (float*)d_out;

    // Workspace layout:
    //   count : N_TOK int            (128 KB)
    //   slots : N_TOK*SLOTS_K ushort (1 MB, 32B-aligned)
    int* count = (int*)d_ws;
    unsigned short* slots = (unsigned short*)(count + N_TOK);

    // Zero the counters every call (deterministic across graph replays).
    hipMemsetAsync(count, 0, (size_t)N_TOK * sizeof(int), stream);

    combine_build<<<N_ROWS / 256, 256, 0, stream>>>(
        token_indices, count, slots);

    combine_gather<<<GATHER_BLOCKS, 256, 0, stream>>>(
        expert_outputs, weights, token_indices, count, slots, out);
}